// Round 6
// baseline (188.869 us; speedup 1.0000x reference)
//
#include <hip/hip_runtime.h>
#include <hip/hip_bf16.h>

// Mex forward: B=64,C=64,H=W=64, BLK=(64,3,3), STR=(64,2,2), PAD=(0,1,1),
// NI=256, EPS=1, mean mode. OH=OW=32, K=576, out (64,256,32,32) fp32.
//
// y[n][i] = log( sum_k exp(P[n][k] + O[i][k]) ) - log(576)
// Shift-invariant -> no max pass. Zero-padded entries -> exp(0)=1.
//
// v6: v5's 2-tile pipeline, but the pipeline unit is ONE oh-row (M=32),
//     needing only 3 staged input rows = 24 KB. Two buffers = 48 KB/block
//     -> 3 blocks/CU (144 KB), 12 waves/CU (+50% vs v5's 8) while KEEPING
//     the pipeline: tile-b's 24 loads are issued before tile-a's barrier
//     (HBM latency hides under kloop_a), epi_a interleaves with kloop_b.
//     Finer phases (144 MFMA, acc=32 regs) + 3 staggered blocks/CU.
// v5: intra-block 2-tile pipeline (was 2 blocks x 80 KB).
// v3: left pad via in-register ones-select; Bt laid out for 1 KB coalesced
//     wave loads; K-loop fully unrolled; B fragments prefetched.

typedef __bf16 bf16x8 __attribute__((ext_vector_type(8)));
typedef float  f32x4  __attribute__((ext_vector_type(4)));

// ---- BtL[(ks*16 + wv*4 + nt)*64 + q*16 + t16][j] = bf16(exp(off[i][c][p]))
// where inst i = wv*64+nt*16+t16, c = c8*8+j, ks = 2*p + (c8>>2), q = c8&3.
__global__ void mex_prep_b(const float* __restrict__ off, __bf16* __restrict__ Bt) {
    const int i = blockIdx.x * 4 + (threadIdx.x >> 6);  // instance
    const int c = threadIdx.x & 63;                     // channel
    const int c8 = c >> 3, j = c & 7;
    const int wv = i >> 6, nt = (i >> 4) & 3, t16 = i & 15;
    const int q  = c8 & 3;
    const float* oi = off + i * 576;
    #pragma unroll
    for (int p = 0; p < 9; ++p) {
        float v = oi[c * 9 + p];                        // original k = c*9 + p
        const int ks    = p * 2 + (c8 >> 2);
        const int chunk = (ks * 16 + wv * 4 + nt) * 64 + q * 16 + t16;
        Bt[chunk * 8 + j] = (__bf16)__expf(v);
    }
}

// ---- main fused kernel ----------------------------------------------------
__global__ __launch_bounds__(256, 3) void mex_main(
        const float* __restrict__ x,
        const __bf16* __restrict__ Bt,
        float* __restrict__ out) {
    // two buffers: [buf 0..1][hl 0..2][w 0..63][chunk 0..7] bf16x8 = 49152 B
    __shared__ bf16x8 lds8[2 * 1536];

    const int bid = blockIdx.x;      // 0..1023
    // XCD-chunked swizzle (1024 % 8 == 0 -> bijective)
    const int wid  = ((bid & 7) << 7) | (bid >> 3);
    const int b    = wid >> 4;
    const int oh_a = (wid & 15) << 1;   // tile a: output row oh_a
    const int oh_b = oh_a + 1;          // tile b: output row oh_a+1
    const int tid  = threadIdx.x;
    const int wv   = tid >> 6;
    const int lane = tid & 63;

    bf16x8 one8;
    #pragma unroll
    for (int j = 0; j < 8; ++j) one8[j] = (__bf16)1.0f;

    // ---- top pad for tile a (h_global = -1), only oh_a == 0 --------------
    if (oh_a == 0) {
        #pragma unroll
        for (int i = 0; i < 2; ++i) lds8[tid + i * 256] = one8;
    }

    // staging geometry: thread t -> w-pair wp (w0 = 2*wp), c-chunk c8.
    // swizzled slot c8 ^ (wp&7) == c8 ^ ((w>>1)&7) for both w0, w0+1.
    const int wp  = tid & 31;
    const int w0  = wp << 1;
    const int c8  = tid >> 5;
    const int c8p = c8 ^ (wp & 7);
    const float* xb = x + ((size_t)b << 18) + w0;   // + c*4096 + h*64

    // ---- stage tile a: x -> exp -> bf16 -> swizzled LDS (chained) --------
    #pragma unroll
    for (int hl = 0; hl < 3; ++hl) {
        const int hg = 2 * oh_a - 1 + hl;           // -1..63
        if (hg >= 0) {                              // block-uniform
            const float* xp = xb + (hg << 6);
            float2 v[8];
            #pragma unroll
            for (int k = 0; k < 8; ++k)
                v[k] = *(const float2*)(xp + (((c8 << 3) + k) << 12));
            bf16x8 ca, cb;
            #pragma unroll
            for (int k = 0; k < 8; ++k) {
                ca[k] = (__bf16)__expf(v[k].x);
                cb[k] = (__bf16)__expf(v[k].y);
            }
            bf16x8* dst = lds8 + hl * 512 + w0 * 8 + c8p;
            dst[0] = ca;        // w = w0
            dst[8] = cb;        // w = w0+1 (same swizzle slot)
        }
    }

    // ---- issue ALL tile b loads now; they fly under tile a's K-loop ------
    // tile b rows: 2*oh_b-1+hl = 2*oh_a+1..2*oh_a+3, never padded.
    float2 v1[24];
    #pragma unroll
    for (int hl = 0; hl < 3; ++hl) {
        const float* xp = xb + ((2 * oh_a + 1 + hl) << 6);
        #pragma unroll
        for (int k = 0; k < 8; ++k)
            v1[hl * 8 + k] = *(const float2*)(xp + (((c8 << 3) + k) << 12));
    }

    // ---- first B fragments -----------------------------------------------
    const bf16x8* __restrict__ Btv = (const bf16x8*)Bt;
    const int wv4 = wv << 2;
    bf16x8 bcur[4];
    #pragma unroll
    for (int nt = 0; nt < 4; ++nt)
        bcur[nt] = Btv[(wv4 + nt) * 64 + lane];     // ks = 0

    const int t16 = tid & 15;
    const int q   = (tid >> 4) & 3;
    int wo2[2];
    #pragma unroll
    for (int mt = 0; mt < 2; ++mt)
        wo2[mt] = (mt * 16 + t16) << 1;   // 2*ow, ow = m = mt*16+t16 (0..31)
    const float lK = 6.356107660695891f;  // log(576)

    // K-loop over one staged 3-row buffer (M=32: 2 mt, acc[2][4])
    auto kloop = [&](const bf16x8* __restrict__ L, f32x4 (&acc)[2][4],
                     bf16x8 (&bc)[4]) {
        #pragma unroll
        for (int ks = 0; ks < 18; ++ks) {
            const int p  = ks >> 1;
            const int fh = (p * 11) >> 5;          // p/3 (const after unroll)
            const int fw = p - fh * 3;
            const int ccq = ((ks & 1) << 2) + q;
            bf16x8 a[2];
            #pragma unroll
            for (int mt = 0; mt < 2; ++mt) {
                const int wc  = wo2[mt] + fw - 1;  // w_global, -1..63
                const int pad = wc < 0;            // only fw==0 & ow==0
                const int wcl = pad ? 0 : wc;
                const int row = fh * 64 + wcl;     // hl = fh (single oh row)
                bf16x8 vv = L[row * 8 + (ccq ^ ((wcl >> 1) & 7))];
                a[mt] = pad ? one8 : vv;
            }
            bf16x8 bnext[4];
            if (ks < 17) {
                #pragma unroll
                for (int nt = 0; nt < 4; ++nt)
                    bnext[nt] = Btv[((ks + 1) * 16 + wv4 + nt) * 64 + lane];
            }
            #pragma unroll
            for (int mt = 0; mt < 2; ++mt)
                #pragma unroll
                for (int nt = 0; nt < 4; ++nt)
                    acc[mt][nt] = __builtin_amdgcn_mfma_f32_16x16x32_bf16(
                        a[mt], bc[nt], acc[mt][nt], 0, 0, 0);
            #pragma unroll
            for (int nt = 0; nt < 4; ++nt) bc[nt] = bnext[nt];
        }
    };

    // direct-store epilogue: y = log(S) - log(576)
    auto epilogue = [&](f32x4 (&acc)[2][4], int oh) {
        #pragma unroll
        for (int mt = 0; mt < 2; ++mt) {
            const int owi  = mt * 16 + (q << 2);   // C/D: row = q*4 + reg
            const int orow = (oh << 5) + owi;
            #pragma unroll
            for (int nt = 0; nt < 4; ++nt) {
                const int inst = wv * 64 + nt * 16 + t16;  // C/D: col = t16
                f32x4 r;
                #pragma unroll
                for (int j = 0; j < 4; ++j)
                    r[j] = __logf(acc[mt][nt][j]) - lK;
                *(f32x4*)(out + (((size_t)b * 256 + inst) * 1024 + orow)) = r;
            }
        }
    };

    __syncthreads();   // B0: buf0 staged

    f32x4 acc0[2][4];
    #pragma unroll
    for (int mt = 0; mt < 2; ++mt)
        #pragma unroll
        for (int nt = 0; nt < 4; ++nt) acc0[mt][nt] = (f32x4)(0.0f);
    kloop(lds8, acc0, bcur);

    // ---- finish-stage tile b (loads landed under kloop_a) ----------------
    #pragma unroll
    for (int hl = 0; hl < 3; ++hl) {
        bf16x8 ca, cb;
        #pragma unroll
        for (int k = 0; k < 8; ++k) {
            ca[k] = (__bf16)__expf(v1[hl * 8 + k].x);
            cb[k] = (__bf16)__expf(v1[hl * 8 + k].y);
        }
        bf16x8* dst = lds8 + 1536 + hl * 512 + w0 * 8 + c8p;
        dst[0] = ca;
        dst[8] = cb;
    }
    #pragma unroll
    for (int nt = 0; nt < 4; ++nt)
        bcur[nt] = Btv[(wv4 + nt) * 64 + lane];     // reload ks = 0

    __syncthreads();   // B1: buf1 staged

    // epilogue(a) shares the scheduling region with kloop(b):
    // logf/global-stores interleave with MFMA/ds_reads.
    epilogue(acc0, oh_a);

    f32x4 acc1[2][4];
    #pragma unroll
    for (int mt = 0; mt < 2; ++mt)
        #pragma unroll
        for (int nt = 0; nt < 4; ++nt) acc1[mt][nt] = (f32x4)(0.0f);
    kloop(lds8 + 1536, acc1, bcur);

    epilogue(acc1, oh_b);
}

extern "C" void kernel_launch(void* const* d_in, const int* in_sizes, int n_in,
                              void* d_out, int out_size, void* d_ws, size_t ws_size,
                              hipStream_t stream) {
    const float* x   = (const float*)d_in[0];   // (64,64,64,64) fp32
    const float* off = (const float*)d_in[1];   // (1,256,64,3,3) fp32
    float* out = (float*)d_out;                 // (64,256,32,32) fp32
    __bf16* Bt = (__bf16*)d_ws;                 // 294912 B

    mex_prep_b<<<64, 256, 0, stream>>>(off, Bt);
    mex_main<<<1024, 256, 0, stream>>>(x, Bt, out);
}

// Round 7
// 150.244 us; speedup vs baseline: 1.2571x; 1.2571x over previous
//
#include <hip/hip_runtime.h>
#include <hip/hip_bf16.h>

// Mex forward: B=64,C=64,H=W=64, BLK=(64,3,3), STR=(64,2,2), PAD=(0,1,1),
// NI=256, EPS=1, mean mode. OH=OW=32, K=576, out (64,256,32,32) fp32.
//
// y[n][i] = log( sum_k exp(P[n][k] + O[i][k]) ) - log(576)
// Shift-invariant -> no max pass. Zero-padded entries -> exp(0)=1.
//
// v7: revert to v5 structure (v6's M=32 tile doubled B-traffic/kloops and
//     regressed 2x). Changes vs v5:
//     - B prefetch distance 2 (b0/b1/b2 rotation): at 2 waves/SIMD a kloop
//       step is ~80 busy cycles but B L2 latency is ~200+ cyc; distance-1
//       prefetch stalled every step on vmcnt. Distance 2 covers it.
//     - epilogue uses nontemporal stores (decisive probe of the 120 MB
//       WRITE_SIZE for a 67 MB output: if unchanged, it's harness memset
//       drain, not our store pattern).
// v5: 2-tile pipeline. Grid 512 x 256thr; each block does two adjacent
//     oh-pair tiles (same b). LDS = 2 x 40 KB (2 blocks/CU = 160 KB).
//     tile1's 40 loads fly under tile0's K-loop; epi0 interleaves with
//     kloop1 in one scheduling region.
// v3: left pad via in-register ones-select; Bt laid out for 1 KB coalesced
//     wave loads; K-loop fully unrolled; B fragments prefetched.

typedef __bf16 bf16x8 __attribute__((ext_vector_type(8)));
typedef float  f32x4  __attribute__((ext_vector_type(4)));

// ---- BtL[(ks*16 + wv*4 + nt)*64 + q*16 + t16][j] = bf16(exp(off[i][c][p]))
// where inst i = wv*64+nt*16+t16, c = c8*8+j, ks = 2*p + (c8>>2), q = c8&3.
__global__ void mex_prep_b(const float* __restrict__ off, __bf16* __restrict__ Bt) {
    const int i = blockIdx.x * 4 + (threadIdx.x >> 6);  // instance
    const int c = threadIdx.x & 63;                     // channel
    const int c8 = c >> 3, j = c & 7;
    const int wv = i >> 6, nt = (i >> 4) & 3, t16 = i & 15;
    const int q  = c8 & 3;
    const float* oi = off + i * 576;
    #pragma unroll
    for (int p = 0; p < 9; ++p) {
        float v = oi[c * 9 + p];                        // original k = c*9 + p
        const int ks    = p * 2 + (c8 >> 2);
        const int chunk = (ks * 16 + wv * 4 + nt) * 64 + q * 16 + t16;
        Bt[chunk * 8 + j] = (__bf16)__expf(v);
    }
}

// ---- main fused kernel ----------------------------------------------------
__global__ __launch_bounds__(256, 2) void mex_main(
        const float* __restrict__ x,
        const __bf16* __restrict__ Bt,
        float* __restrict__ out) {
    // two buffers: [buf 0..1][hl 0..4][w 0..63][chunk 0..7] bf16x8 = 81920 B
    __shared__ bf16x8 lds8[2 * 2560];

    const int bid = blockIdx.x;      // 0..511
    // XCD-chunked swizzle (512 % 8 == 0 -> bijective)
    const int wid  = ((bid & 7) << 6) | (bid >> 3);
    const int b    = wid >> 3;
    const int j2   = wid & 7;
    const int oh0a = j2 << 2;        // tile0: oh rows oh0a, oh0a+1
    const int oh0b = oh0a + 2;       // tile1: oh rows oh0b, oh0b+1
    const int tid  = threadIdx.x;
    const int wv   = tid >> 6;
    const int lane = tid & 63;

    bf16x8 one8;
    #pragma unroll
    for (int j = 0; j < 8; ++j) one8[j] = (__bf16)1.0f;

    // ---- top pad for tile0 (h_global = -1), only j2 == 0 -----------------
    if (oh0a == 0) {
        #pragma unroll
        for (int i = 0; i < 2; ++i) lds8[tid + i * 256] = one8;
    }

    // staging geometry: thread t -> w-pair wp (w0 = 2*wp), c-chunk c8.
    // swizzled slot c8 ^ (wp&7) == c8 ^ ((w>>1)&7) for both w0, w0+1.
    const int wp  = tid & 31;
    const int w0  = wp << 1;
    const int c8  = tid >> 5;
    const int c8p = c8 ^ (wp & 7);
    const float* xb = x + ((size_t)b << 18) + w0;   // + c*4096 + h*64

    // ---- stage tile0: x -> exp -> bf16 -> swizzled LDS (chained) ---------
    #pragma unroll
    for (int hl = 0; hl < 5; ++hl) {
        const int hg = 2 * oh0a - 1 + hl;           // -1..31
        if (hg >= 0) {                              // block-uniform
            const float* xp = xb + (hg << 6);
            float2 v[8];
            #pragma unroll
            for (int k = 0; k < 8; ++k)
                v[k] = *(const float2*)(xp + (((c8 << 3) + k) << 12));
            bf16x8 ca, cb;
            #pragma unroll
            for (int k = 0; k < 8; ++k) {
                ca[k] = (__bf16)__expf(v[k].x);
                cb[k] = (__bf16)__expf(v[k].y);
            }
            bf16x8* dst = lds8 + hl * 512 + w0 * 8 + c8p;
            dst[0] = ca;        // w = w0
            dst[8] = cb;        // w = w0+1 (same swizzle slot)
        }
    }

    // ---- issue ALL tile1 loads now; they fly under tile0's K-loop --------
    float2 v1[40];
    #pragma unroll
    for (int hl = 0; hl < 5; ++hl) {
        const int hg = 2 * oh0b - 1 + hl;           // 3..63, never padded
        const float* xp = xb + (hg << 6);
        #pragma unroll
        for (int k = 0; k < 8; ++k)
            v1[hl * 8 + k] = *(const float2*)(xp + (((c8 << 3) + k) << 12));
    }

    // ---- first B fragments (distance-2 pipeline) -------------------------
    const bf16x8* __restrict__ Btv = (const bf16x8*)Bt;
    const int wv4 = wv << 2;
    bf16x8 b0[4], b1[4];
    #pragma unroll
    for (int nt = 0; nt < 4; ++nt) {
        b0[nt] = Btv[(wv4 + nt) * 64 + lane];            // ks = 0
        b1[nt] = Btv[(16 + wv4 + nt) * 64 + lane];       // ks = 1
    }

    const int t16 = tid & 15;
    const int q   = (tid >> 4) & 3;
    int hb[4], wo2[4];
    #pragma unroll
    for (int mt = 0; mt < 4; ++mt) {
        const int m = mt * 16 + t16;
        wo2[mt] = (m & 31) << 1;      // 2*ow
        hb[mt]  = (m >> 5) << 7;      // (2*ohl) * 64
    }
    const float lK = 6.356107660695891f;   // log(576)

    // K-loop over one staged buffer; B rotates through b0/b1/b2 (dist 2)
    auto kloop = [&](const bf16x8* __restrict__ L, f32x4 (&acc)[4][4],
                     bf16x8 (&bc)[4], bf16x8 (&bn)[4]) {
        #pragma unroll
        for (int ks = 0; ks < 18; ++ks) {
            const int p  = ks >> 1;
            const int fh = (p * 11) >> 5;          // p/3 (const after unroll)
            const int fw = p - fh * 3;
            const int ccq = ((ks & 1) << 2) + q;
            bf16x8 a[4];
            #pragma unroll
            for (int mt = 0; mt < 4; ++mt) {
                const int wc  = wo2[mt] + fw - 1;  // w_global, -1..63
                const int pad = wc < 0;            // only fw==0 & ow==0
                const int wcl = pad ? 0 : wc;
                const int row = hb[mt] + fh * 64 + wcl;  // (2*ohl+fh)*64 + w
                bf16x8 vv = L[row * 8 + (ccq ^ ((wcl >> 1) & 7))];
                a[mt] = pad ? one8 : vv;
            }
            bf16x8 b2[4];
            if (ks < 16) {
                #pragma unroll
                for (int nt = 0; nt < 4; ++nt)
                    b2[nt] = Btv[((ks + 2) * 16 + wv4 + nt) * 64 + lane];
            }
            #pragma unroll
            for (int mt = 0; mt < 4; ++mt)
                #pragma unroll
                for (int nt = 0; nt < 4; ++nt)
                    acc[mt][nt] = __builtin_amdgcn_mfma_f32_16x16x32_bf16(
                        a[mt], bc[nt], acc[mt][nt], 0, 0, 0);
            #pragma unroll
            for (int nt = 0; nt < 4; ++nt) { bc[nt] = bn[nt]; bn[nt] = b2[nt]; }
        }
    };

    // direct nontemporal-store epilogue: y = log(S) - log(576)
    auto epilogue = [&](f32x4 (&acc)[4][4], int oh0) {
        #pragma unroll
        for (int mt = 0; mt < 4; ++mt) {
            const int m   = mt * 16 + (q << 2);    // C/D: row = q*4 + reg
            const int ohl = m >> 5;
            const int owi = m & 31;
            const int orow = (oh0 + ohl) * 32 + owi;
            #pragma unroll
            for (int nt = 0; nt < 4; ++nt) {
                const int inst = wv * 64 + nt * 16 + t16;  // C/D: col = t16
                f32x4 r;
                #pragma unroll
                for (int j = 0; j < 4; ++j)
                    r[j] = __logf(acc[mt][nt][j]) - lK;
                __builtin_nontemporal_store(
                    r, (f32x4*)(out + (((size_t)b * 256 + inst) * 1024 + orow)));
            }
        }
    };

    __syncthreads();   // B0: buf0 staged

    f32x4 acc0[4][4];
    #pragma unroll
    for (int mt = 0; mt < 4; ++mt)
        #pragma unroll
        for (int nt = 0; nt < 4; ++nt) acc0[mt][nt] = (f32x4)(0.0f);
    kloop(lds8, acc0, b0, b1);

    // ---- finish-stage tile1 (loads have landed under the K-loop) ---------
    #pragma unroll
    for (int hl = 0; hl < 5; ++hl) {
        bf16x8 ca, cb;
        #pragma unroll
        for (int k = 0; k < 8; ++k) {
            ca[k] = (__bf16)__expf(v1[hl * 8 + k].x);
            cb[k] = (__bf16)__expf(v1[hl * 8 + k].y);
        }
        bf16x8* dst = lds8 + 2560 + hl * 512 + w0 * 8 + c8p;
        dst[0] = ca;
        dst[8] = cb;
    }
    #pragma unroll
    for (int nt = 0; nt < 4; ++nt) {
        b0[nt] = Btv[(wv4 + nt) * 64 + lane];            // ks = 0
        b1[nt] = Btv[(16 + wv4 + nt) * 64 + lane];       // ks = 1
    }

    __syncthreads();   // B1: buf1 staged

    // epilogue(t0) sits in the same scheduling region as kloop(t1):
    // logf/global-stores interleave with MFMA/ds_reads.
    epilogue(acc0, oh0a);

    f32x4 acc1[4][4];
    #pragma unroll
    for (int mt = 0; mt < 4; ++mt)
        #pragma unroll
        for (int nt = 0; nt < 4; ++nt) acc1[mt][nt] = (f32x4)(0.0f);
    kloop(lds8 + 2560, acc1, b0, b1);

    epilogue(acc1, oh0b);
}

extern "C" void kernel_launch(void* const* d_in, const int* in_sizes, int n_in,
                              void* d_out, int out_size, void* d_ws, size_t ws_size,
                              hipStream_t stream) {
    const float* x   = (const float*)d_in[0];   // (64,64,64,64) fp32
    const float* off = (const float*)d_in[1];   // (1,256,64,3,3) fp32
    float* out = (float*)d_out;                 // (64,256,32,32) fp32
    __bf16* Bt = (__bf16*)d_ws;                 // 294912 B

    mex_prep_b<<<64, 256, 0, stream>>>(off, Bt);
    mex_main<<<512, 256, 0, stream>>>(x, Bt, out);
}